// Round 1
// baseline (735.490 us; speedup 1.0000x reference)
//
#include <hip/hip_runtime.h>
#include <math.h>

#define LN      2048
#define LOG2L   11
#define BB      16
#define HH      8
#define EE      64
#define HE      512            // HH*EE
#define KTOP    7              // int(log(2048)) = 7
#define CH_PER_WG 8
#define NWG_A   (BB * (HE / CH_PER_WG))   // 1024
#define TWO_PI  6.283185307179586f

__device__ __forceinline__ unsigned bitrev11(unsigned x) {
    return __brev(x) >> (32 - LOG2L);
}

// ---------------------------------------------------------------------------
// Kernel A: per-channel FFT of z = q + i*k, extract S = Q*conj(K), accumulate
// sum over channels into per-b spectrum via atomics.
// ---------------------------------------------------------------------------
__global__ __launch_bounds__(256) void fft_corr_kernel(
    const float* __restrict__ q, const float* __restrict__ k,
    float* __restrict__ spec /* [BB][LN][2] */) {
    __shared__ float2 zbuf[LN];
    __shared__ float2 acc[LN];
    __shared__ float2 tw[LN / 2];

    const int tid  = threadIdx.x;
    const int wg   = blockIdx.x;
    const int b    = wg / (HE / CH_PER_WG);
    const int c0   = (wg % (HE / CH_PER_WG)) * CH_PER_WG;

    for (int p = tid; p < LN / 2; p += 256) {
        float s, c;
        sincosf(-TWO_PI * (float)p / (float)LN, &s, &c);
        tw[p] = make_float2(c, s);
    }
    for (int f = tid; f < LN; f += 256) acc[f] = make_float2(0.f, 0.f);
    __syncthreads();

    for (int cc = 0; cc < CH_PER_WG; ++cc) {
        const int c = c0 + cc;
        const size_t base = (size_t)b * LN * HE + c;
        // load z = q + i*k into bit-reversed positions
        for (int t = tid; t < LN; t += 256) {
            float qr = q[base + (size_t)t * HE];
            float ki = k[base + (size_t)t * HE];
            zbuf[bitrev11((unsigned)t)] = make_float2(qr, ki);
        }
        __syncthreads();
        // radix-2 DIT FFT (forward)
        for (int s = 0; s < LOG2L; ++s) {
            const int half = 1 << s;
            for (int j = tid; j < LN / 2; j += 256) {
                const int grp = j >> s;
                const int pos = j & (half - 1);
                const int i0  = (grp << (s + 1)) + pos;
                const int i1  = i0 + half;
                const float2 w = tw[pos << (LOG2L - 1 - s)];
                float2 a  = zbuf[i0];
                float2 bv = zbuf[i1];
                float tr = w.x * bv.x - w.y * bv.y;
                float ti = w.x * bv.y + w.y * bv.x;
                zbuf[i0] = make_float2(a.x + tr, a.y + ti);
                zbuf[i1] = make_float2(a.x - tr, a.y - ti);
            }
            __syncthreads();
        }
        // extract Q, K from packed transform; S = Q * conj(K); accumulate
        for (int f = tid; f < LN; f += 256) {
            float2 zf = zbuf[f];
            float2 zm = zbuf[(LN - f) & (LN - 1)];
            float crx = zm.x, cry = -zm.y;           // conj(Z[L-f])
            float Qr = 0.5f * (zf.x + crx);
            float Qi = 0.5f * (zf.y + cry);
            float dx = zf.x - crx, dy = zf.y - cry;  // Z[f]-conj(Z[L-f]) = 2i K
            float Kr = 0.5f * dy;
            float Ki = -0.5f * dx;
            float Sr = Qr * Kr + Qi * Ki;
            float Si = Qi * Kr - Qr * Ki;
            float2 a = acc[f];
            acc[f] = make_float2(a.x + Sr, a.y + Si);
        }
        __syncthreads();
    }
    for (int f = tid; f < LN; f += 256) {
        atomicAdd(&spec[((size_t)b * LN + f) * 2 + 0], acc[f].x);
        atomicAdd(&spec[((size_t)b * LN + f) * 2 + 1], acc[f].y);
    }
}

// ---------------------------------------------------------------------------
// Kernel B: per-b inverse transform of summed spectrum -> mean corr,
// top-7 (tie-break lowest index) + softmax -> weights + delays.
// ---------------------------------------------------------------------------
__global__ __launch_bounds__(256) void icorr_topk_kernel(
    const float* __restrict__ spec, float* __restrict__ wts, int* __restrict__ tao) {
    __shared__ float2 zbuf[LN];
    __shared__ float2 tw[LN / 2];
    __shared__ float  cr[LN];
    __shared__ float  rv[256];
    __shared__ int    ri[256];
    __shared__ float  topv[KTOP];
    __shared__ int    topi[KTOP];

    const int tid = threadIdx.x;
    const int b   = blockIdx.x;

    for (int p = tid; p < LN / 2; p += 256) {
        float s, c;
        sincosf(-TWO_PI * (float)p / (float)LN, &s, &c);
        tw[p] = make_float2(c, s);
    }
    // idft(S) = conj(dft(conj(S)))/L -> load conj(S) bit-reversed, forward FFT
    for (int f = tid; f < LN; f += 256) {
        float sr = spec[((size_t)b * LN + f) * 2 + 0];
        float si = spec[((size_t)b * LN + f) * 2 + 1];
        zbuf[bitrev11((unsigned)f)] = make_float2(sr, -si);
    }
    __syncthreads();
    for (int s = 0; s < LOG2L; ++s) {
        const int half = 1 << s;
        for (int j = tid; j < LN / 2; j += 256) {
            const int grp = j >> s;
            const int pos = j & (half - 1);
            const int i0  = (grp << (s + 1)) + pos;
            const int i1  = i0 + half;
            const float2 w = tw[pos << (LOG2L - 1 - s)];
            float2 a  = zbuf[i0];
            float2 bv = zbuf[i1];
            float tr = w.x * bv.x - w.y * bv.y;
            float ti = w.x * bv.y + w.y * bv.x;
            zbuf[i0] = make_float2(a.x + tr, a.y + ti);
            zbuf[i1] = make_float2(a.x - tr, a.y - ti);
        }
        __syncthreads();
    }
    const float scale = 1.0f / ((float)LN * (float)HE);
    for (int t = tid; t < LN; t += 256) cr[t] = zbuf[t].x * scale;
    __syncthreads();

    // top-7 via repeated parallel argmax (ties -> lowest index, like lax.top_k)
    for (int it = 0; it < KTOP; ++it) {
        float mv = -INFINITY;
        int   mi = 0;
        for (int t = tid; t < LN; t += 256) {
            float v = cr[t];
            if (v > mv) { mv = v; mi = t; }
        }
        rv[tid] = mv; ri[tid] = mi;
        __syncthreads();
        for (int off = 128; off > 0; off >>= 1) {
            if (tid < off) {
                float ov = rv[tid + off]; int oi = ri[tid + off];
                if (ov > rv[tid] || (ov == rv[tid] && oi < ri[tid])) {
                    rv[tid] = ov; ri[tid] = oi;
                }
            }
            __syncthreads();
        }
        if (tid == 0) {
            topv[it] = rv[0];
            topi[it] = ri[0];
            cr[ri[0]] = -INFINITY;
        }
        __syncthreads();
    }
    if (tid == 0) {
        float m = topv[0];
        float s = 0.f;
        float ex[KTOP];
        for (int j = 0; j < KTOP; ++j) { ex[j] = __expf(topv[j] - m); s += ex[j]; }
        float inv = 1.0f / s;
        for (int j = 0; j < KTOP; ++j) {
            wts[b * 8 + j] = ex[j] * inv;
            tao[b * 8 + j] = topi[j];
        }
    }
}

// ---------------------------------------------------------------------------
// Kernel C: out[b,l,:,:] = sum_j w[b,j] * V[b,(l+tao_j)%L,:,:]   (float4)
// ---------------------------------------------------------------------------
__global__ __launch_bounds__(256) void gather_kernel(
    const float* __restrict__ v, const float* __restrict__ wts,
    const int* __restrict__ tao, float* __restrict__ out) {
    __shared__ float lw[KTOP];
    __shared__ int   lt[KTOP];
    const int tid = threadIdx.x;
    const long long idx = (long long)blockIdx.x * 256 + tid;   // float4 index
    const int c4 = (int)(idx & 127);            // 128 float4 per (b,l) row
    const int l  = (int)((idx >> 7) & (LN - 1));
    const int b  = (int)(idx >> 18);
    if (tid < KTOP) {
        lw[tid] = wts[b * 8 + tid];
        lt[tid] = tao[b * 8 + tid];
    }
    __syncthreads();
    const float4* v4 = (const float4*)v;
    float4 a = make_float4(0.f, 0.f, 0.f, 0.f);
    #pragma unroll
    for (int j = 0; j < KTOP; ++j) {
        int ls = (l + lt[j]) & (LN - 1);
        float4 x = v4[((size_t)b * LN + ls) * 128 + c4];
        float w = lw[j];
        a.x += w * x.x; a.y += w * x.y; a.z += w * x.z; a.w += w * x.w;
    }
    ((float4*)out)[idx] = a;
}

// ---------------------------------------------------------------------------
extern "C" void kernel_launch(void* const* d_in, const int* in_sizes, int n_in,
                              void* d_out, int out_size, void* d_ws, size_t ws_size,
                              hipStream_t stream) {
    const float* q = (const float*)d_in[0];
    const float* k = (const float*)d_in[1];
    const float* v = (const float*)d_in[2];
    float* out  = (float*)d_out;
    float* spec = (float*)d_ws;                 // BB*LN*2 floats = 256 KB
    float* wts  = spec + (size_t)BB * LN * 2;   // BB*8 floats
    int*   tao  = (int*)(wts + BB * 8);         // BB*8 ints

    hipMemsetAsync(spec, 0, (size_t)BB * LN * 2 * sizeof(float), stream);
    fft_corr_kernel<<<NWG_A, 256, 0, stream>>>(q, k, spec);
    icorr_topk_kernel<<<BB, 256, 0, stream>>>(spec, wts, tao);
    const int n4 = BB * LN * HE / 4;            // 4,194,304 float4 outputs
    gather_kernel<<<n4 / 256, 256, 0, stream>>>(v, wts, tao, out);
}

// Round 2
// 200.657 us; speedup vs baseline: 3.6654x; 3.6654x over previous
//
#include <hip/hip_runtime.h>
#include <math.h>

#define LN      2048
#define LOG2L   11
#define BB      16
#define HE      512            // H*E channels
#define KTOP    7              // int(log(2048)) = 7
#define CH_PER_WG 8
#define NWG_A   (BB * (HE / CH_PER_WG))   // 1024
#define TWO_PI  6.283185307179586f

// pad-swizzle for LDS FFT buffers: breaks power-of-2 stride conflicts
#define PHI(i)  ((i) + ((i) >> 4))
#define PHYS    2176            // PHI(2047)=2174, round up

__device__ __forceinline__ unsigned bitrev11(unsigned x) {
    return __brev(x) >> (32 - LOG2L);
}

// ---------------------------------------------------------------------------
// Kernel T: coalesced transpose+split. q,k [b][l][c] -> qT,kT [b][c][l].
// 64x64 tiles via LDS. Every global access is wave-contiguous.
// ---------------------------------------------------------------------------
__global__ __launch_bounds__(256) void transpose_pack_kernel(
    const float* __restrict__ q, const float* __restrict__ k,
    float* __restrict__ qT, float* __restrict__ kT) {
    __shared__ float2 tile[64][65];
    const int tid = threadIdx.x;
    const int bid = blockIdx.x;
    const int b  = bid >> 8;           // 32 l-tiles * 8 c-tiles = 256 per b
    const int lt = (bid >> 3) & 31;
    const int ct = bid & 7;
    const int l0 = lt << 6, c0 = ct << 6;
    const int col = tid & 63, row = tid >> 6;   // row 0..3
    #pragma unroll
    for (int rr = 0; rr < 16; ++rr) {
        const int r = (rr << 2) + row;          // 0..63 (l offset)
        const size_t src = ((size_t)(b * LN + l0 + r)) * HE + c0 + col;
        tile[r][col] = make_float2(q[src], k[src]);
    }
    __syncthreads();
    #pragma unroll
    for (int rr = 0; rr < 16; ++rr) {
        const int r = (rr << 2) + row;          // 0..63 (c offset)
        const float2 v = tile[col][r];
        const size_t dst = ((size_t)(b * HE + c0 + r)) * LN + l0 + col;
        qT[dst] = v.x;
        kT[dst] = v.y;
    }
}

// ---------------------------------------------------------------------------
// Kernel A (fast): per-channel Stockham FFT (5x radix-4 + radix-2) of
// z = q + i*k from the transposed layout; extract S = Q*conj(K); accumulate
// per-thread in registers; one atomicAdd set per WG at the end.
// ---------------------------------------------------------------------------
__global__ __launch_bounds__(256) void fft4_corr_kernel(
    const float* __restrict__ qT, const float* __restrict__ kT,
    float* __restrict__ spec /* [BB][LN][2] */) {
    __shared__ float2 bufA[PHYS];
    __shared__ float2 bufB[PHYS];
    __shared__ float2 tw[LN / 2];

    const int tid = threadIdx.x;
    const int wg  = blockIdx.x;
    const int b   = wg / (HE / CH_PER_WG);
    const int c0  = (wg % (HE / CH_PER_WG)) * CH_PER_WG;

    for (int p = tid; p < LN / 2; p += 256) {
        float s, c;
        sincosf(-TWO_PI * (float)p / (float)LN, &s, &c);
        tw[p] = make_float2(c, s);
    }
    float accx[8], accy[8];
    #pragma unroll
    for (int i = 0; i < 8; ++i) { accx[i] = 0.f; accy[i] = 0.f; }
    __syncthreads();

    for (int cc = 0; cc < CH_PER_WG; ++cc) {
        const size_t base = ((size_t)(b * HE + c0 + cc)) << LOG2L;
        for (int t = tid; t < LN; t += 256)
            bufA[PHI(t)] = make_float2(qT[base + t], kT[base + t]);
        __syncthreads();

        float2* X = bufA;
        float2* Y = bufB;
        // 5 radix-4 Stockham DIF stages: l=512>>2s, m=4^s, natural in/out order
        #pragma unroll
        for (int s = 0; s < 5; ++s) {
            const int m = 1 << (2 * s);
            #pragma unroll
            for (int j0 = 0; j0 < 512; j0 += 256) {
                const int j  = j0 + tid;
                const int p  = j >> (2 * s);
                const int q_ = j & (m - 1);
                const float2 a  = X[PHI(j)];
                const float2 bv = X[PHI(j + 512)];
                const float2 cv = X[PHI(j + 1024)];
                const float2 dv = X[PHI(j + 1536)];
                const float t0x = a.x + cv.x,  t0y = a.y + cv.y;
                const float t1x = a.x - cv.x,  t1y = a.y - cv.y;
                const float t2x = bv.x + dv.x, t2y = bv.y + dv.y;
                const float t3x = bv.y - dv.y, t3y = dv.x - bv.x;   // -i*(b-d)
                const float2 w1 = tw[p << (2 * s)];
                const float2 w2 = tw[p << (2 * s + 1)];
                const float w3x = w1.x * w2.x - w1.y * w2.y;
                const float w3y = w1.x * w2.y + w1.y * w2.x;
                const int ob = q_ + ((j - q_) << 2);   // q + 4*m*p
                const float y1x = t1x + t3x, y1y = t1y + t3y;
                const float y2x = t0x - t2x, y2y = t0y - t2y;
                const float y3x = t1x - t3x, y3y = t1y - t3y;
                Y[PHI(ob)]         = make_float2(t0x + t2x, t0y + t2y);
                Y[PHI(ob + m)]     = make_float2(w1.x * y1x - w1.y * y1y,
                                                 w1.x * y1y + w1.y * y1x);
                Y[PHI(ob + 2 * m)] = make_float2(w2.x * y2x - w2.y * y2y,
                                                 w2.x * y2y + w2.y * y2x);
                Y[PHI(ob + 3 * m)] = make_float2(w3x * y3x - w3y * y3y,
                                                 w3x * y3y + w3y * y3x);
            }
            __syncthreads();
            float2* t = X; X = Y; Y = t;
        }
        // final radix-2 stage (twiddle = 1), X -> Y
        #pragma unroll
        for (int j0 = 0; j0 < 1024; j0 += 256) {
            const int j = j0 + tid;
            const float2 a  = X[PHI(j)];
            const float2 bv = X[PHI(j + 1024)];
            Y[PHI(j)]        = make_float2(a.x + bv.x, a.y + bv.y);
            Y[PHI(j + 1024)] = make_float2(a.x - bv.x, a.y - bv.y);
        }
        __syncthreads();
        const float2* R = Y;   // result buffer, natural order

        // unpack Q,K; S = Q*conj(K); accumulate in registers
        #pragma unroll
        for (int i = 0; i < 8; ++i) {
            const int f = tid + (i << 8);
            const float2 zf = R[PHI(f)];
            const float2 zm = R[PHI((LN - f) & (LN - 1))];
            const float Qr = 0.5f * (zf.x + zm.x);
            const float Qi = 0.5f * (zf.y - zm.y);
            const float dx = zf.x - zm.x, dy = zf.y + zm.y;
            const float Kr = 0.5f * dy;
            const float Ki = -0.5f * dx;
            accx[i] += Qr * Kr + Qi * Ki;
            accy[i] += Qi * Kr - Qr * Ki;
        }
        __syncthreads();   // before next channel overwrites bufA
    }
    #pragma unroll
    for (int i = 0; i < 8; ++i) {
        const int f = tid + (i << 8);
        atomicAdd(&spec[((size_t)b * LN + f) * 2 + 0], accx[i]);
        atomicAdd(&spec[((size_t)b * LN + f) * 2 + 1], accy[i]);
    }
}

// ---------------------------------------------------------------------------
// Kernel A (fallback, round-1): uncoalesced direct FFT. Used only if ws is
// too small for the transposed staging buffers.
// ---------------------------------------------------------------------------
__global__ __launch_bounds__(256) void fft_corr_kernel(
    const float* __restrict__ q, const float* __restrict__ k,
    float* __restrict__ spec) {
    __shared__ float2 zbuf[LN];
    __shared__ float2 acc[LN];
    __shared__ float2 tw[LN / 2];
    const int tid = threadIdx.x;
    const int wg  = blockIdx.x;
    const int b   = wg / (HE / CH_PER_WG);
    const int c0  = (wg % (HE / CH_PER_WG)) * CH_PER_WG;
    for (int p = tid; p < LN / 2; p += 256) {
        float s, c;
        sincosf(-TWO_PI * (float)p / (float)LN, &s, &c);
        tw[p] = make_float2(c, s);
    }
    for (int f = tid; f < LN; f += 256) acc[f] = make_float2(0.f, 0.f);
    __syncthreads();
    for (int cc = 0; cc < CH_PER_WG; ++cc) {
        const int c = c0 + cc;
        const size_t base = (size_t)b * LN * HE + c;
        for (int t = tid; t < LN; t += 256) {
            float qr = q[base + (size_t)t * HE];
            float ki = k[base + (size_t)t * HE];
            zbuf[bitrev11((unsigned)t)] = make_float2(qr, ki);
        }
        __syncthreads();
        for (int s = 0; s < LOG2L; ++s) {
            const int half = 1 << s;
            for (int j = tid; j < LN / 2; j += 256) {
                const int grp = j >> s;
                const int pos = j & (half - 1);
                const int i0  = (grp << (s + 1)) + pos;
                const int i1  = i0 + half;
                const float2 w = tw[pos << (LOG2L - 1 - s)];
                float2 a  = zbuf[i0];
                float2 bv = zbuf[i1];
                float tr = w.x * bv.x - w.y * bv.y;
                float ti = w.x * bv.y + w.y * bv.x;
                zbuf[i0] = make_float2(a.x + tr, a.y + ti);
                zbuf[i1] = make_float2(a.x - tr, a.y - ti);
            }
            __syncthreads();
        }
        for (int f = tid; f < LN; f += 256) {
            float2 zf = zbuf[f];
            float2 zm = zbuf[(LN - f) & (LN - 1)];
            float crx = zm.x, cry = -zm.y;
            float Qr = 0.5f * (zf.x + crx);
            float Qi = 0.5f * (zf.y + cry);
            float dx = zf.x - crx, dy = zf.y - cry;
            float Kr = 0.5f * dy;
            float Ki = -0.5f * dx;
            float2 a = acc[f];
            acc[f] = make_float2(a.x + (Qr * Kr + Qi * Ki), a.y + (Qi * Kr - Qr * Ki));
        }
        __syncthreads();
    }
    for (int f = tid; f < LN; f += 256) {
        atomicAdd(&spec[((size_t)b * LN + f) * 2 + 0], acc[f].x);
        atomicAdd(&spec[((size_t)b * LN + f) * 2 + 1], acc[f].y);
    }
}

// ---------------------------------------------------------------------------
// Kernel B: per-b inverse transform of summed spectrum -> mean corr,
// top-7 + softmax -> weights + delays. (tiny: 16 WGs)
// ---------------------------------------------------------------------------
__global__ __launch_bounds__(256) void icorr_topk_kernel(
    const float* __restrict__ spec, float* __restrict__ wts, int* __restrict__ tao) {
    __shared__ float2 zbuf[LN];
    __shared__ float2 tw[LN / 2];
    __shared__ float  cr[LN];
    __shared__ float  rv[256];
    __shared__ int    ri[256];
    __shared__ float  topv[KTOP];
    __shared__ int    topi[KTOP];
    const int tid = threadIdx.x;
    const int b   = blockIdx.x;
    for (int p = tid; p < LN / 2; p += 256) {
        float s, c;
        sincosf(-TWO_PI * (float)p / (float)LN, &s, &c);
        tw[p] = make_float2(c, s);
    }
    for (int f = tid; f < LN; f += 256) {
        float sr = spec[((size_t)b * LN + f) * 2 + 0];
        float si = spec[((size_t)b * LN + f) * 2 + 1];
        zbuf[bitrev11((unsigned)f)] = make_float2(sr, -si);
    }
    __syncthreads();
    for (int s = 0; s < LOG2L; ++s) {
        const int half = 1 << s;
        for (int j = tid; j < LN / 2; j += 256) {
            const int grp = j >> s;
            const int pos = j & (half - 1);
            const int i0  = (grp << (s + 1)) + pos;
            const int i1  = i0 + half;
            const float2 w = tw[pos << (LOG2L - 1 - s)];
            float2 a  = zbuf[i0];
            float2 bv = zbuf[i1];
            float tr = w.x * bv.x - w.y * bv.y;
            float ti = w.x * bv.y + w.y * bv.x;
            zbuf[i0] = make_float2(a.x + tr, a.y + ti);
            zbuf[i1] = make_float2(a.x - tr, a.y - ti);
        }
        __syncthreads();
    }
    const float scale = 1.0f / ((float)LN * (float)HE);
    for (int t = tid; t < LN; t += 256) cr[t] = zbuf[t].x * scale;
    __syncthreads();
    for (int it = 0; it < KTOP; ++it) {
        float mv = -INFINITY;
        int   mi = 0;
        for (int t = tid; t < LN; t += 256) {
            float v = cr[t];
            if (v > mv) { mv = v; mi = t; }
        }
        rv[tid] = mv; ri[tid] = mi;
        __syncthreads();
        for (int off = 128; off > 0; off >>= 1) {
            if (tid < off) {
                float ov = rv[tid + off]; int oi = ri[tid + off];
                if (ov > rv[tid] || (ov == rv[tid] && oi < ri[tid])) {
                    rv[tid] = ov; ri[tid] = oi;
                }
            }
            __syncthreads();
        }
        if (tid == 0) {
            topv[it] = rv[0];
            topi[it] = ri[0];
            cr[ri[0]] = -INFINITY;
        }
        __syncthreads();
    }
    if (tid == 0) {
        float m = topv[0];
        float s = 0.f;
        float ex[KTOP];
        for (int j = 0; j < KTOP; ++j) { ex[j] = __expf(topv[j] - m); s += ex[j]; }
        float inv = 1.0f / s;
        for (int j = 0; j < KTOP; ++j) {
            wts[b * 8 + j] = ex[j] * inv;
            tao[b * 8 + j] = topi[j];
        }
    }
}

// ---------------------------------------------------------------------------
// Kernel C: out[b,l,:,:] = sum_j w[b,j] * V[b,(l+tao_j)%L,:,:]   (float4)
// ---------------------------------------------------------------------------
__global__ __launch_bounds__(256) void gather_kernel(
    const float* __restrict__ v, const float* __restrict__ wts,
    const int* __restrict__ tao, float* __restrict__ out) {
    __shared__ float lw[KTOP];
    __shared__ int   lt[KTOP];
    const int tid = threadIdx.x;
    const long long idx = (long long)blockIdx.x * 256 + tid;   // float4 index
    const int c4 = (int)(idx & 127);
    const int l  = (int)((idx >> 7) & (LN - 1));
    const int b  = (int)(idx >> 18);
    if (tid < KTOP) {
        lw[tid] = wts[b * 8 + tid];
        lt[tid] = tao[b * 8 + tid];
    }
    __syncthreads();
    const float4* v4 = (const float4*)v;
    float4 a = make_float4(0.f, 0.f, 0.f, 0.f);
    #pragma unroll
    for (int j = 0; j < KTOP; ++j) {
        int ls = (l + lt[j]) & (LN - 1);
        float4 x = v4[((size_t)b * LN + ls) * 128 + c4];
        float w = lw[j];
        a.x += w * x.x; a.y += w * x.y; a.z += w * x.z; a.w += w * x.w;
    }
    ((float4*)out)[idx] = a;
}

// ---------------------------------------------------------------------------
extern "C" void kernel_launch(void* const* d_in, const int* in_sizes, int n_in,
                              void* d_out, int out_size, void* d_ws, size_t ws_size,
                              hipStream_t stream) {
    const float* q = (const float*)d_in[0];
    const float* k = (const float*)d_in[1];
    const float* v = (const float*)d_in[2];
    float* out = (float*)d_out;

    const size_t nT   = (size_t)BB * HE * LN;          // 16.7M floats = 64 MB
    const size_t need = nT * 4 + (size_t)BB * LN * 2 * 4 + (size_t)BB * 8 * 8;

    if (ws_size >= need) {
        // fast path: qT staged in d_out (fully overwritten by gather later)
        float* kT   = (float*)d_ws;
        float* spec = kT + nT;
        float* wts  = spec + (size_t)BB * LN * 2;
        int*   tao  = (int*)(wts + BB * 8);
        float* qT   = out;

        hipMemsetAsync(spec, 0, (size_t)BB * LN * 2 * sizeof(float), stream);
        transpose_pack_kernel<<<BB * 32 * 8, 256, 0, stream>>>(q, k, qT, kT);
        fft4_corr_kernel<<<NWG_A, 256, 0, stream>>>(qT, kT, spec);
        icorr_topk_kernel<<<BB, 256, 0, stream>>>(spec, wts, tao);
        const int n4 = BB * LN * HE / 4;
        gather_kernel<<<n4 / 256, 256, 0, stream>>>(v, wts, tao, out);
    } else {
        // fallback: round-1 path (correct, slower)
        float* spec = (float*)d_ws;
        float* wts  = spec + (size_t)BB * LN * 2;
        int*   tao  = (int*)(wts + BB * 8);
        hipMemsetAsync(spec, 0, (size_t)BB * LN * 2 * sizeof(float), stream);
        fft_corr_kernel<<<NWG_A, 256, 0, stream>>>(q, k, spec);
        icorr_topk_kernel<<<BB, 256, 0, stream>>>(spec, wts, tao);
        const int n4 = BB * LN * HE / 4;
        gather_kernel<<<n4 / 256, 256, 0, stream>>>(v, wts, tao, out);
    }
}